// Round 9
// baseline (261.901 us; speedup 1.0000x reference)
//
#include <hip/hip_runtime.h>
#include <hip/hip_bf16.h>

constexpr int N_NODES = 50000;
constexpr int N_EDGES = 800000;
constexpr int F_IN = 128;
constexpr int H1 = 64;
constexpr int HEADS = 4;
constexpr int D_H = 32;
constexpr int HOUT = HEADS * D_H;       // 128
constexpr int N_REL = 4;
constexpr int N_GRAPHS = 64;
constexpr int MBIG = H1 * (1 + N_REL);  // 320
constexpr int NBLK = (N_NODES + 255) / 256;  // 196
constexpr int N_PAD = 50048;            // rows padded to grid multiple (64*782)

typedef __attribute__((ext_vector_type(8))) short bf16x8;
typedef __attribute__((ext_vector_type(4))) float f32x4;

// ---- monotonic float<->uint for atomicMax on floats ----
__device__ __forceinline__ unsigned f2mono(float f) {
  unsigned u = __float_as_uint(f);
  return (u & 0x80000000u) ? ~u : (u | 0x80000000u);
}
__device__ __forceinline__ float mono2f(unsigned m) {
  unsigned u = (m & 0x80000000u) ? (m & 0x7FFFFFFFu) : ~m;
  return __uint_as_float(u);
}
constexpr unsigned MONO_NEG_INF = 0x007FFFFFu;

// ---- bf16 helpers ----
__device__ __forceinline__ unsigned short f2bf(float f) {
  unsigned u = __float_as_uint(f);
  unsigned r = (u + 0x7FFFu + ((u >> 16) & 1u)) >> 16;  // RNE
  return (unsigned short)r;
}
__device__ __forceinline__ float bf2f(unsigned short h) {
  return __uint_as_float((unsigned)h << 16);
}
__device__ __forceinline__ float bflo(unsigned u) { return __uint_as_float(u << 16); }
__device__ __forceinline__ float bfhi(unsigned u) { return __uint_as_float(u & 0xFFFF0000u); }

// ---- build transposed bf16 hi/lo weights ----
__global__ __launch_bounds__(256) void build_wT(const float* __restrict__ W_root,
                                                const float* __restrict__ W_rel,
                                                const float* __restrict__ W_gat,
                                                unsigned short* __restrict__ WbT_hi,
                                                unsigned short* __restrict__ WbT_lo,
                                                unsigned short* __restrict__ WgT_hi,
                                                unsigned short* __restrict__ WgT_lo) {
  int i = blockIdx.x * 256 + threadIdx.x;
  if (i < MBIG * F_IN) {               // WbigT[c][k]
    int c = i / F_IN, k = i % F_IN;
    float w = (c < H1) ? W_root[k * H1 + c]
                       : W_rel[((size_t)(((c - H1) >> 6) * F_IN + k)) * H1 + ((c - H1) & 63)];
    unsigned short hi = f2bf(w);
    WbT_hi[i] = hi;
    WbT_lo[i] = f2bf(w - bf2f(hi));
  } else {
    int j = i - MBIG * F_IN;
    if (j < HOUT * H1) {               // WgatT[c][k]
      int c = j / H1, k = j % H1;
      float w = W_gat[k * HOUT + c];
      unsigned short hi = f2bf(w);
      WgT_hi[j] = hi;
      WgT_lo[j] = f2bf(w - bf2f(hi));
    }
  }
}

// ---- split-bf16 MFMA GEMM, register-direct (no LDS, no barriers).
//      Block = 4 waves x 16 rows = 64 rows. Per wave: A f32 row-fragments
//      loaded from global + converted to bf16 hi/lo IN REGISTER (once per
//      row in the whole grid), then col-loop over M/16 output fragments
//      with B hi/lo fragments read from global (L1/L2-hot). ----
template <int K>
__global__ __launch_bounds__(256) void gemm_reg(const float* __restrict__ A,
                                                const unsigned short* __restrict__ BT_hi,
                                                const unsigned short* __restrict__ BT_lo,
                                                unsigned short* __restrict__ Cbf,
                                                int N, int M) {
  constexpr int NKS = K / 32;
  const int tid = threadIdx.x;
  const int wv = tid >> 6, lane = tid & 63;
  const int lrow = lane & 15, lkc = lane >> 4;
  const int row0 = blockIdx.x * 64 + wv * 16;
  // A fragments: row = row0+lrow, k = ksi*32 + lkc*8 + [0..7]
  int ar = row0 + lrow;
  const float* ap = A + (size_t)((ar < N) ? ar : 0) * K;  // clamp OOB rows
  bf16x8 ah[NKS], al[NKS];
#pragma unroll
  for (int ksi = 0; ksi < NKS; ++ksi) {
    float4 v0 = *reinterpret_cast<const float4*>(ap + ksi * 32 + lkc * 8);
    float4 v1 = *reinterpret_cast<const float4*>(ap + ksi * 32 + lkc * 8 + 4);
    float vv[8] = {v0.x, v0.y, v0.z, v0.w, v1.x, v1.y, v1.z, v1.w};
    bf16x8 hh, ll;
#pragma unroll
    for (int j = 0; j < 8; ++j) {
      unsigned short hb = f2bf(vv[j]);
      hh[j] = (short)hb;
      ll[j] = (short)f2bf(vv[j] - bf2f(hb));
    }
    ah[ksi] = hh;
    al[ksi] = ll;
  }
  // column loop: one 16x16 output fragment per iteration
  for (int cb = 0; cb < M; cb += 16) {
    const unsigned short* bp_hi = BT_hi + (size_t)(cb + lrow) * K + lkc * 8;
    const unsigned short* bp_lo = BT_lo + (size_t)(cb + lrow) * K + lkc * 8;
    f32x4 acc = {};
#pragma unroll
    for (int ksi = 0; ksi < NKS; ++ksi) {
      bf16x8 bh = *reinterpret_cast<const bf16x8*>(bp_hi + ksi * 32);
      bf16x8 bl = *reinterpret_cast<const bf16x8*>(bp_lo + ksi * 32);
      acc = __builtin_amdgcn_mfma_f32_16x16x32_bf16(ah[ksi], bh, acc, 0, 0, 0);
      acc = __builtin_amdgcn_mfma_f32_16x16x32_bf16(ah[ksi], bl, acc, 0, 0, 0);
      acc = __builtin_amdgcn_mfma_f32_16x16x32_bf16(al[ksi], bh, acc, 0, 0, 0);
    }
    // C/D: col = lane&15, row = (lane>>4)*4 + i
#pragma unroll
    for (int i = 0; i < 4; ++i) {
      int row = row0 + lkc * 4 + i;
      if (row < N) Cbf[(size_t)row * M + cb + lrow] = f2bf(acc[i]);
    }
  }
}

// ---- CSR build: histogram of dst + per-edge rank (coalesced store) ----
__global__ __launch_bounds__(256) void k_hist(const int* __restrict__ dst,
                                              int* __restrict__ deg,
                                              int* __restrict__ rank) {
  int e = blockIdx.x * 256 + threadIdx.x;
  if (e < N_EDGES) rank[e] = atomicAdd(&deg[dst[e]], 1);
}

// ---- scan stage 1: per-block sums ----
__global__ __launch_bounds__(256) void k_s1(const int* __restrict__ deg,
                                            int* __restrict__ bsum) {
  __shared__ int ss[256];
  int t = threadIdx.x;
  int i = blockIdx.x * 256 + t;
  ss[t] = (i < N_NODES) ? deg[i] : 0;
  __syncthreads();
  for (int d = 128; d > 0; d >>= 1) {
    if (t < d) ss[t] += ss[t + d];
    __syncthreads();
  }
  if (t == 0) bsum[blockIdx.x] = ss[0];
}

// ---- scan stage 2: exclusive scan of block sums ----
__global__ __launch_bounds__(256) void k_s2(const int* __restrict__ bsum,
                                            int* __restrict__ bbase,
                                            int* __restrict__ off) {
  __shared__ int ss[256];
  int t = threadIdx.x;
  int v = (t < NBLK) ? bsum[t] : 0;
  ss[t] = v;
  __syncthreads();
  for (int d = 1; d < 256; d <<= 1) {
    int u = (t >= d) ? ss[t - d] : 0;
    __syncthreads();
    ss[t] += u;
    __syncthreads();
  }
  if (t < NBLK) bbase[t] = ss[t] - v;
  if (t == NBLK - 1) off[N_NODES] = ss[t];
}

// ---- scan stage 3: block-local scan + base ----
__global__ __launch_bounds__(256) void k_s3(const int* __restrict__ deg,
                                            const int* __restrict__ bbase,
                                            int* __restrict__ off) {
  __shared__ int ss[256];
  int t = threadIdx.x;
  int i = blockIdx.x * 256 + t;
  int v = (i < N_NODES) ? deg[i] : 0;
  ss[t] = v;
  __syncthreads();
  for (int d = 1; d < 256; d <<= 1) {
    int u = (t >= d) ? ss[t - d] : 0;
    __syncthreads();
    ss[t] += u;
    __syncthreads();
  }
  if (i < N_NODES) off[i] = bbase[blockIdx.x] + ss[t] - v;
}

// ---- CSR fill: atomic-free — pos = off[dst] + rank; scatter store ----
__global__ __launch_bounds__(256) void k_fill(const int* __restrict__ src,
                                              const int* __restrict__ dst,
                                              const int* __restrict__ etype,
                                              const int* __restrict__ off,
                                              const int* __restrict__ rank,
                                              int* __restrict__ eprep) {
  int e = blockIdx.x * 256 + threadIdx.x;
  if (e >= N_EDGES) return;
  int pos = off[dst[e]] + rank[e];
  eprep[pos] = src[e] | (etype[e] << 16);
}

// ---- RGCN: gather from bf16 xt; wave/node; 2 edges/iter, x2 unroll ----
__global__ __launch_bounds__(256) void rgcn_gather(const unsigned short* __restrict__ xtbf,
                                                   const int* __restrict__ off,
                                                   const int* __restrict__ eprep,
                                                   const float* __restrict__ b_rgcn,
                                                   float* __restrict__ h) {
  int wid = (blockIdx.x * 256 + threadIdx.x) >> 6;
  int lane = threadIdx.x & 63;
  int half = lane >> 5;
  int cp = lane & 31;
  int start = off[wid], end = off[wid + 1];
  float a0x=0.f,a0y=0.f,a1x=0.f,a1y=0.f,a2x=0.f,a2y=0.f,a3x=0.f,a3y=0.f;
  int c0=0,c1=0,c2=0,c3=0;
  int niter = (end - start + 1) >> 1;
  for (int t = 0; t < niter; t += 2) {
    int idx0 = start + 2 * t + half;
    int idx1 = idx0 + 2;
    int p0 = (idx0 < end) ? eprep[idx0] : 0x70000;
    int p1 = (idx1 < end) ? eprep[idx1] : 0x70000;
    int s0 = p0 & 0xFFFF, r0 = p0 >> 16;
    int s1 = p1 & 0xFFFF, r1 = p1 >> 16;
    unsigned u0 = *reinterpret_cast<const unsigned*>(
        &xtbf[(size_t)s0 * MBIG + H1 + (r0 << 6) + cp * 2]);
    unsigned u1 = *reinterpret_cast<const unsigned*>(
        &xtbf[(size_t)s1 * MBIG + H1 + (r1 << 6) + cp * 2]);
    float v0x = bflo(u0), v0y = bfhi(u0);
    float v1x = bflo(u1), v1y = bfhi(u1);
    a0x += (r0==0)?v0x:0.f; a0y += (r0==0)?v0y:0.f; c0 += (r0==0);
    a1x += (r0==1)?v0x:0.f; a1y += (r0==1)?v0y:0.f; c1 += (r0==1);
    a2x += (r0==2)?v0x:0.f; a2y += (r0==2)?v0y:0.f; c2 += (r0==2);
    a3x += (r0==3)?v0x:0.f; a3y += (r0==3)?v0y:0.f; c3 += (r0==3);
    a0x += (r1==0)?v1x:0.f; a0y += (r1==0)?v1y:0.f; c0 += (r1==0);
    a1x += (r1==1)?v1x:0.f; a1y += (r1==1)?v1y:0.f; c1 += (r1==1);
    a2x += (r1==2)?v1x:0.f; a2y += (r1==2)?v1y:0.f; c2 += (r1==2);
    a3x += (r1==3)?v1x:0.f; a3y += (r1==3)?v1y:0.f; c3 += (r1==3);
  }
  a0x += __shfl_xor(a0x, 32); a0y += __shfl_xor(a0y, 32);
  a1x += __shfl_xor(a1x, 32); a1y += __shfl_xor(a1y, 32);
  a2x += __shfl_xor(a2x, 32); a2y += __shfl_xor(a2y, 32);
  a3x += __shfl_xor(a3x, 32); a3y += __shfl_xor(a3y, 32);
  c0 += __shfl_xor(c0, 32); c1 += __shfl_xor(c1, 32);
  c2 += __shfl_xor(c2, 32); c3 += __shfl_xor(c3, 32);
  if (half == 0) {
    unsigned ur = *reinterpret_cast<const unsigned*>(&xtbf[(size_t)wid * MBIG + cp * 2]);
    float2 bb = *reinterpret_cast<const float2*>(&b_rgcn[cp * 2]);
    float i0 = 1.0f / (float)max(c0, 1);
    float i1 = 1.0f / (float)max(c1, 1);
    float i2 = 1.0f / (float)max(c2, 1);
    float i3 = 1.0f / (float)max(c3, 1);
    float vx = bflo(ur) + bb.x + a0x * i0 + a1x * i1 + a2x * i2 + a3x * i3;
    float vy = bfhi(ur) + bb.y + a0y * i0 + a1y * i1 + a2y * i2 + a3y * i3;
    *reinterpret_cast<float2*>(&h[(size_t)wid * H1 + cp * 2]) =
        make_float2(fmaxf(vx, 0.f), fmaxf(vy, 0.f));
  }
}

// ---- attention coefficients from bf16 g, LDS-staged ----
__global__ __launch_bounds__(256) void gat_att(const unsigned short* __restrict__ gbf,
                                               const float* __restrict__ att_src,
                                               const float* __restrict__ att_dst,
                                               float* __restrict__ a_s,
                                               float* __restrict__ a_d) {
  __shared__ float gs[64][129];
  __shared__ float asrc[HOUT], adst[HOUT];
  int t = threadIdx.x;
  if (t < HOUT) { asrc[t] = att_src[t]; adst[t] = att_dst[t]; }
  int nb = blockIdx.x * 64;
#pragma unroll
  for (int it = 0; it < 8; ++it) {
    int idx = it * 256 + t;
    int r = idx >> 5, c4 = (idx & 31) * 4;
    int gn = nb + r;
    uint2 v = make_uint2(0u, 0u);
    if (gn < N_NODES)
      v = *reinterpret_cast<const uint2*>(&gbf[(size_t)gn * HOUT + c4]);
    gs[r][c4 + 0] = bflo(v.x); gs[r][c4 + 1] = bfhi(v.x);
    gs[r][c4 + 2] = bflo(v.y); gs[r][c4 + 3] = bfhi(v.y);
  }
  __syncthreads();
  int n = t & 63, hh = t >> 6;
  float s = 0.f, d = 0.f;
#pragma unroll
  for (int k = 0; k < D_H; ++k) {
    float gv = gs[n][hh * D_H + k];
    s += gv * asrc[hh * D_H + k];
    d += gv * adst[hh * D_H + k];
  }
  if (nb + n < N_NODES) {
    a_s[(size_t)(nb + n) * 4 + hh] = s;
    a_d[(size_t)(nb + n) * 4 + hh] = d;
  }
}

// ---- init mono buffer ----
__global__ __launch_bounds__(256) void init_mono(unsigned* __restrict__ p, int count) {
  int i = blockIdx.x * 256 + threadIdx.x;
  if (i < count) p[i] = MONO_NEG_INF;
}

// ---- GAT + head fused ----
constexpr int GAT_BLOCKS = 2048;
constexpr int GAT_WAVES = GAT_BLOCKS * 4;   // 8192
__global__ __launch_bounds__(256) void gat_fused(const unsigned short* __restrict__ gbf,
                                                 const float* __restrict__ a_s,
                                                 const float* __restrict__ a_d,
                                                 const int* __restrict__ off,
                                                 const int* __restrict__ eprep,
                                                 const float* __restrict__ b_gat,
                                                 const float* __restrict__ W1,
                                                 const float* __restrict__ b1,
                                                 const int* __restrict__ batch,
                                                 unsigned* __restrict__ p_mono) {
  __shared__ float w1s[HOUT * 16];        // W1[k][j]
  __shared__ float ob[4][HOUT];           // per-wave o row
  __shared__ unsigned sp[N_GRAPHS * 16];
  const int t = threadIdx.x;
  for (int i = t; i < HOUT * 16; i += 256) w1s[i] = W1[i];
  for (int i = t; i < N_GRAPHS * 16; i += 256) sp[i] = MONO_NEG_INF;
  __syncthreads();
  const int wv = t >> 6, lane = t & 63;
  const int hh = lane >> 4;
  const int jj = lane & 15, grp = lane >> 4;
  const int w = blockIdx.x * 4 + wv;
  const int q = N_NODES / GAT_WAVES;
  const int r = N_NODES % GAT_WAVES;
  const int nbeg = w * q + ((w < r) ? w : r);
  const int ncnt = q + ((w < r) ? 1 : 0);
  for (int wid = nbeg; wid < nbeg + ncnt; ++wid) {
    int start = off[wid], end = off[wid + 1];
    float4 ad4 = *reinterpret_cast<const float4*>(a_d + (size_t)wid * 4);
    float adh = (hh == 0) ? ad4.x : (hh == 1) ? ad4.y : (hh == 2) ? ad4.z : ad4.w;
    float ox = 0.f, oy = 0.f, den = 0.f;
    int i = start;
    for (; i + 4 <= end; i += 4) {
      int p0 = eprep[i], p1 = eprep[i + 1], p2 = eprep[i + 2], p3 = eprep[i + 3];
      int s0 = p0 & 0xFFFF, s1 = p1 & 0xFFFF, s2 = p2 & 0xFFFF, s3 = p3 & 0xFFFF;
      float as0 = a_s[(size_t)s0 * 4 + hh];
      float as1 = a_s[(size_t)s1 * 4 + hh];
      float as2 = a_s[(size_t)s2 * 4 + hh];
      float as3 = a_s[(size_t)s3 * 4 + hh];
      unsigned u0 = *reinterpret_cast<const unsigned*>(&gbf[(size_t)s0 * HOUT + lane * 2]);
      unsigned u1 = *reinterpret_cast<const unsigned*>(&gbf[(size_t)s1 * HOUT + lane * 2]);
      unsigned u2 = *reinterpret_cast<const unsigned*>(&gbf[(size_t)s2 * HOUT + lane * 2]);
      unsigned u3 = *reinterpret_cast<const unsigned*>(&gbf[(size_t)s3 * HOUT + lane * 2]);
      float e0 = as0 + adh; e0 = (e0 > 0.f) ? e0 : 0.2f * e0;
      float e1 = as1 + adh; e1 = (e1 > 0.f) ? e1 : 0.2f * e1;
      float e2 = as2 + adh; e2 = (e2 > 0.f) ? e2 : 0.2f * e2;
      float e3 = as3 + adh; e3 = (e3 > 0.f) ? e3 : 0.2f * e3;
      float x0 = __expf(e0), x1 = __expf(e1), x2 = __expf(e2), x3 = __expf(e3);
      den += x0 + x1 + x2 + x3;
      ox += x0 * bflo(u0) + x1 * bflo(u1) + x2 * bflo(u2) + x3 * bflo(u3);
      oy += x0 * bfhi(u0) + x1 * bfhi(u1) + x2 * bfhi(u2) + x3 * bfhi(u3);
    }
    for (; i < end; ++i) {
      int p = eprep[i];
      int s = p & 0xFFFF;
      float as = a_s[(size_t)s * 4 + hh];
      unsigned u = *reinterpret_cast<const unsigned*>(&gbf[(size_t)s * HOUT + lane * 2]);
      float e = as + adh; e = (e > 0.f) ? e : 0.2f * e;
      float ex = __expf(e);
      den += ex;
      ox += ex * bflo(u);
      oy += ex * bfhi(u);
    }
    float dinv = (den > 0.f) ? (1.0f / den) : 0.f;
    float2 bg = *reinterpret_cast<const float2*>(b_gat + lane * 2);
    float vx = ox * dinv + bg.x; vx = (vx > 0.f) ? vx : 0.01f * vx;
    float vy = oy * dinv + bg.y; vy = (vy > 0.f) ? vy : 0.01f * vy;
    *reinterpret_cast<float2*>(&ob[wv][lane * 2]) = make_float2(vx, vy);
    float acc = 0.f;
#pragma unroll 8
    for (int i2 = 0; i2 < 32; ++i2) {
      int c = grp + 4 * i2;
      acc += ob[wv][c] * w1s[c * 16 + jj];
    }
    acc += __shfl_xor(acc, 16);
    acc += __shfl_xor(acc, 32);
    float z = acc + b1[jj];
    z = (z > 0.f) ? z : 0.01f * z;
    int b = batch[wid];
    if (lane < 16) atomicMax(&sp[b * 16 + jj], f2mono(z));
  }
  __syncthreads();
  for (int i = t; i < N_GRAPHS * 16; i += 256) {
    unsigned v = sp[i];
    if (v != MONO_NEG_INF) atomicMax(p_mono + i, v);
  }
}

// ---- y = p @ W2 + b2 ----
__global__ void final_y(const unsigned* __restrict__ p_mono,
                        const float* __restrict__ W2,
                        const float* __restrict__ b2,
                        float* __restrict__ y) {
  int gr = threadIdx.x;
  if (gr >= N_GRAPHS) return;
  float acc = b2[0];
#pragma unroll
  for (int k = 0; k < 16; ++k) acc += mono2f(p_mono[gr * 16 + k]) * W2[k];
  y[gr] = acc;
}

extern "C" void kernel_launch(void* const* d_in, const int* in_sizes, int n_in,
                              void* d_out, int out_size, void* d_ws, size_t ws_size,
                              hipStream_t stream) {
  const float* x       = (const float*)d_in[0];
  const int*   eidx    = (const int*)d_in[1];
  const int*   etype   = (const int*)d_in[2];
  const int*   batch   = (const int*)d_in[3];
  const float* W_rel   = (const float*)d_in[4];
  const float* W_root  = (const float*)d_in[5];
  const float* b_rgcn  = (const float*)d_in[6];
  const float* W_gat   = (const float*)d_in[7];
  const float* att_src = (const float*)d_in[8];
  const float* att_dst = (const float*)d_in[9];
  const float* b_gat   = (const float*)d_in[10];
  const float* W1      = (const float*)d_in[11];
  const float* b1      = (const float*)d_in[12];
  const float* W2      = (const float*)d_in[13];
  const float* b2      = (const float*)d_in[14];
  float* y = (float*)d_out;

  const int* src = eidx;
  const int* dst = eidx + N_EDGES;

  float* ws = (float*)d_ws;
  // ---- workspace layout (float offsets); buffers padded to N_PAD rows ----
  const size_t OFF_XTBF= 0;           //  8,007,680 f: xt bf16 [N_PAD,320]
  const size_t OFF_GBF = 0;           //  g bf16 [N_PAD,128] (reuses xtbf)
  const size_t OFF_H   = 8007680;     //  3,203,072  h [N_PAD,64] f32
  const size_t OFF_AS  = 11210752;    //    200,000  a_src
  const size_t OFF_AD  = 11410752;    //    200,000  a_dst
  const size_t OFF_PM  = 11610752;    //        256  pool max (1024 u32)
  const size_t OFF_DEG = 11611008;    //     50,000  deg (int)
  const size_t OFF_OFFS= 11661008;    //     50,001  off (int)
  const size_t OFF_RANK= 11711016;    //    800,000  rank (int)
  const size_t OFF_EP  = 12511016;    //    800,000  eprep (int)
  const size_t OFF_BS  = 13311016;    //        196
  const size_t OFF_BB  = 13311212;    //        196
  const size_t OFF_WBH = 13311412;    //     20,480  WbigT_hi (byte off %16==0)
  const size_t OFF_WBL = 13331892;    //     20,480  WbigT_lo
  const size_t OFF_WGH = 13352372;    //      4,096  WgatT_hi
  const size_t OFF_WGL = 13356468;    //      4,096  WgatT_lo
  const size_t TOTAL_F = 13360564;
  if (ws_size < TOTAL_F * sizeof(float)) return;

  unsigned short* xtbf = (unsigned short*)(ws + OFF_XTBF);
  unsigned short* gbf  = (unsigned short*)(ws + OFF_GBF);
  float* h     = ws + OFF_H;
  float* a_s   = ws + OFF_AS;
  float* a_d   = ws + OFF_AD;
  unsigned* pm = (unsigned*)(ws + OFF_PM);
  int* deg     = (int*)(ws + OFF_DEG);
  int* offs    = (int*)(ws + OFF_OFFS);
  int* rank    = (int*)(ws + OFF_RANK);
  int* eprep   = (int*)(ws + OFF_EP);
  int* bsum    = (int*)(ws + OFF_BS);
  int* bbase   = (int*)(ws + OFF_BB);
  unsigned short* wbt_hi = (unsigned short*)(ws + OFF_WBH);
  unsigned short* wbt_lo = (unsigned short*)(ws + OFF_WBL);
  unsigned short* wgt_hi = (unsigned short*)(ws + OFF_WGH);
  unsigned short* wgt_lo = (unsigned short*)(ws + OFF_WGL);

  // CSR build (atomic-free fill)
  hipMemsetAsync(deg, 0, N_NODES * sizeof(int), stream);
  k_hist<<<(N_EDGES + 255) / 256, 256, 0, stream>>>(dst, deg, rank);
  k_s1<<<NBLK, 256, 0, stream>>>(deg, bsum);
  k_s2<<<1, 256, 0, stream>>>(bsum, bbase, offs);
  k_s3<<<NBLK, 256, 0, stream>>>(deg, bbase, offs);
  k_fill<<<(N_EDGES + 255) / 256, 256, 0, stream>>>(src, dst, etype, offs, rank, eprep);

  // transposed bf16 hi/lo weights
  build_wT<<<(MBIG * F_IN + HOUT * H1 + 255) / 256, 256, 0, stream>>>(
      W_root, W_rel, W_gat, wbt_hi, wbt_lo, wgt_hi, wgt_lo);

  // xt(bf16) = x @ [W_root | W_rel]  (register-direct MFMA GEMM)
  gemm_reg<128><<<N_PAD / 64, 256, 0, stream>>>(x, wbt_hi, wbt_lo, xtbf,
                                                N_NODES, MBIG);

  // RGCN gather -> h (f32)
  rgcn_gather<<<N_NODES / 4, 256, 0, stream>>>(xtbf, offs, eprep, b_rgcn, h);

  // g(bf16) = h @ W_gat
  gemm_reg<64><<<N_PAD / 64, 256, 0, stream>>>(h, wgt_hi, wgt_lo, gbf,
                                               N_NODES, HOUT);

  // attention coefficients
  gat_att<<<(N_NODES + 63) / 64, 256, 0, stream>>>(gbf, att_src, att_dst, a_s, a_d);

  // fused GAT aggregation + head + per-graph max pool
  init_mono<<<(N_GRAPHS * 16 + 255) / 256, 256, 0, stream>>>(pm, N_GRAPHS * 16);
  gat_fused<<<GAT_BLOCKS, 256, 0, stream>>>(gbf, a_s, a_d, offs, eprep, b_gat,
                                            W1, b1, batch, pm);

  // y = p @ W2 + b2
  final_y<<<1, 64, 0, stream>>>(pm, W2, b2, y);
}